// Round 1
// baseline (526.917 us; speedup 1.0000x reference)
//
#include <hip/hip_runtime.h>
#include <math.h>

#define SEQ   2048
#define BATCH 64
#define HDIM  512
#define EDIM  256
#define VOCAB 50257
#define BH    (BATCH * HDIM)   // 32768

// ---------------------------------------------------------------------------
// Kernel 1: flash-style attention partials.
// grid (P/4, BATCH), block 256 (4 waves). Each wave owns one partial p for
// batch b: online softmax over its seq chunk, acc[512] spread 8 floats/lane.
// ---------------------------------------------------------------------------
__global__ __launch_bounds__(256)
void attn_partial(const float* __restrict__ enc, const float* __restrict__ dec,
                  float* __restrict__ pm, float* __restrict__ pl,
                  float* __restrict__ pacc, int P, int rows) {
    const int lane = threadIdx.x & 63;
    const int wave = threadIdx.x >> 6;
    const int p = blockIdx.x * 4 + wave;
    const int b = blockIdx.y;
    const int s0 = p * rows;
    const float scale = 0.044194173824159216f; // 1/sqrt(512)

    // q = dec_hidden[1][b][8*lane .. 8*lane+7]
    const float4* qp = (const float4*)(dec + BH + (size_t)b * HDIM + 8 * lane);
    float4 q0 = qp[0], q1 = qp[1];
    float qa[8] = {q0.x, q0.y, q0.z, q0.w, q1.x, q1.y, q1.z, q1.w};

    float m = -INFINITY, l = 0.f;
    float acc[8] = {0.f, 0.f, 0.f, 0.f, 0.f, 0.f, 0.f, 0.f};

    for (int r = 0; r < rows; r += 4) {
        float va[4][8];
        #pragma unroll
        for (int j = 0; j < 4; ++j) {
            const float4* vp = (const float4*)(enc +
                ((size_t)(s0 + r + j) * BATCH + b) * HDIM + 8 * lane);
            float4 t0 = vp[0], t1 = vp[1];
            va[j][0] = t0.x; va[j][1] = t0.y; va[j][2] = t0.z; va[j][3] = t0.w;
            va[j][4] = t1.x; va[j][5] = t1.y; va[j][6] = t1.z; va[j][7] = t1.w;
        }
        float e[4];
        #pragma unroll
        for (int j = 0; j < 4; ++j) {
            float d = 0.f;
            #pragma unroll
            for (int i = 0; i < 8; ++i) d = fmaf(va[j][i], qa[i], d);
            e[j] = d;
        }
        // interleaved wave reductions (6 xor steps each)
        #pragma unroll
        for (int off = 32; off > 0; off >>= 1) {
            #pragma unroll
            for (int j = 0; j < 4; ++j) e[j] += __shfl_xor(e[j], off, 64);
        }
        #pragma unroll
        for (int j = 0; j < 4; ++j) {
            float ej = e[j] * scale;
            float mn = fmaxf(m, ej);
            float f  = __expf(m - mn);   // exp(-inf)=0 on first row
            float wj = __expf(ej - mn);
            l = l * f + wj;
            #pragma unroll
            for (int i = 0; i < 8; ++i) acc[i] = acc[i] * f + wj * va[j][i];
            m = mn;
        }
    }

    float* pa = pacc + ((size_t)b * P + p) * HDIM + 8 * lane;
    #pragma unroll
    for (int i = 0; i < 8; ++i) pa[i] = acc[i];
    if (lane == 0) { pm[b * P + p] = m; pl[b * P + p] = l; }
}

// ---------------------------------------------------------------------------
// Kernel 2: combine partials -> context; build xT = [emb; ctx] (k-major),
// plus transposed dec_hidden layers hT0/hT1. grid 64 (=b), block 512 (=h).
// ---------------------------------------------------------------------------
__global__ __launch_bounds__(512)
void attn_combine(const float* __restrict__ pm, const float* __restrict__ pl,
                  const float* __restrict__ pacc, const float* __restrict__ dec,
                  const float* __restrict__ emb, const int* __restrict__ inputs,
                  float* __restrict__ xT, float* __restrict__ hT0,
                  float* __restrict__ hT1, int P) {
    __shared__ float s_coef[64];
    __shared__ float s_inv;
    const int b = blockIdx.x;
    const int t = threadIdx.x;

    if (t == 0) {
        float m = -INFINITY;
        for (int p = 0; p < P; ++p) m = fmaxf(m, pm[b * P + p]);
        float denom = 0.f;
        for (int p = 0; p < P; ++p) {
            float c = __expf(pm[b * P + p] - m);
            s_coef[p] = c;
            denom += c * pl[b * P + p];
        }
        s_inv = 1.f / denom;
    }
    __syncthreads();

    float c = 0.f;
    const float* pa = pacc + (size_t)b * P * HDIM + t;
    for (int p = 0; p < P; ++p) c += s_coef[p] * pa[(size_t)p * HDIM];
    float ctx = c * s_inv;

    xT[(EDIM + t) * BATCH + b] = ctx;
    if (t < EDIM) xT[t * BATCH + b] = emb[(size_t)inputs[b] * EDIM + t];
    hT0[t * BATCH + b] = dec[(size_t)b * HDIM + t];
    hT1[t * BATCH + b] = dec[BH + (size_t)b * HDIM + t];
}

// ---------------------------------------------------------------------------
// Kernel 3: GRU cell. grid 128, block 256; wave-uniform h (scalar W loads),
// lane = batch (coalesced xT/hprevT loads). Writes h_out row-major + transposed.
// ---------------------------------------------------------------------------
__global__ __launch_bounds__(256)
void gru_cell(const float* __restrict__ xT, int K1,
              const float* __restrict__ Wih, const float* __restrict__ bih,
              const float* __restrict__ hprev, const float* __restrict__ hprevT,
              const float* __restrict__ Whh, const float* __restrict__ bhh,
              float* __restrict__ hout, float* __restrict__ houtT) {
    const int lane = threadIdx.x & 63;
    const int h = blockIdx.x * 4 + (threadIdx.x >> 6);

    const float* wr = Wih + (size_t)h * K1;
    const float* wz = Wih + (size_t)(HDIM + h) * K1;
    const float* wn = Wih + (size_t)(2 * HDIM + h) * K1;
    float ar = 0.f, az = 0.f, an = 0.f;
    #pragma unroll 4
    for (int k = 0; k < K1; ++k) {
        float xv = xT[k * BATCH + lane];
        ar = fmaf(wr[k], xv, ar);
        az = fmaf(wz[k], xv, az);
        an = fmaf(wn[k], xv, an);
    }

    const float* ur = Whh + (size_t)h * HDIM;
    const float* uz = Whh + (size_t)(HDIM + h) * HDIM;
    const float* un = Whh + (size_t)(2 * HDIM + h) * HDIM;
    float hr = 0.f, hz = 0.f, hn = 0.f;
    #pragma unroll 4
    for (int k = 0; k < HDIM; ++k) {
        float hv = hprevT[k * BATCH + lane];
        hr = fmaf(ur[k], hv, hr);
        hz = fmaf(uz[k], hv, hz);
        hn = fmaf(un[k], hv, hn);
    }

    float gr  = ar + bih[h]            + hr + bhh[h];
    float gz  = az + bih[HDIM + h]     + hz + bhh[HDIM + h];
    float gin = an + bih[2 * HDIM + h];
    float ghn = hn + bhh[2 * HDIM + h];
    float r = 1.f / (1.f + __expf(-gr));
    float z = 1.f / (1.f + __expf(-gz));
    float n = tanhf(gin + r * ghn);
    float hp = hprev[(size_t)lane * HDIM + h];
    float hnew = (1.f - z) * n + z * hp;

    hout[(size_t)lane * HDIM + h] = hnew;
    houtT[(size_t)h * BATCH + lane] = hnew;
}

// ---------------------------------------------------------------------------
// Kernel 4: vocab projection logits = h1 @ out_W^T + out_b.
// h1 staged in LDS as bf16 (64KB -> 2 blocks/CU). lane = batch; each wave
// handles 8 consecutive vocab rows (wave-uniform scalar weight streams).
// ---------------------------------------------------------------------------
__global__ __launch_bounds__(512)
void vocab_proj(const float* __restrict__ h1T, const float* __restrict__ Wout,
                const float* __restrict__ bout, float* __restrict__ logits) {
    __shared__ unsigned short sh[HDIM * BATCH]; // 64KB bf16 h1T, [k][b]
    const int t = threadIdx.x;
    for (int i = t; i < HDIM * BATCH; i += 512) {
        unsigned int u = __float_as_uint(h1T[i]);
        unsigned int r = (u + 0x7fffu + ((u >> 16) & 1u)) >> 16; // RNE
        sh[i] = (unsigned short)r;
    }
    __syncthreads();

    const int lane = t & 63;
    const int wave = t >> 6;
    const int v0 = (blockIdx.x * 8 + wave) * 8;

    const float* wp[8];
    #pragma unroll
    for (int i = 0; i < 8; ++i) {
        int vi = min(v0 + i, VOCAB - 1); // clamp: safe loads, guarded stores
        wp[i] = Wout + (size_t)vi * HDIM;
    }
    float acc[8] = {0.f, 0.f, 0.f, 0.f, 0.f, 0.f, 0.f, 0.f};
    #pragma unroll 8
    for (int k = 0; k < HDIM; ++k) {
        float hv = __uint_as_float((unsigned int)sh[k * BATCH + lane] << 16);
        #pragma unroll
        for (int i = 0; i < 8; ++i) acc[i] = fmaf(wp[i][k], hv, acc[i]);
    }
    float* orow = logits + (size_t)lane * VOCAB;
    #pragma unroll
    for (int i = 0; i < 8; ++i) {
        int v = v0 + i;
        if (v < VOCAB) orow[v] = acc[i] + bout[v];
    }
}

// ---------------------------------------------------------------------------
extern "C" void kernel_launch(void* const* d_in, const int* in_sizes, int n_in,
                              void* d_out, int out_size, void* d_ws, size_t ws_size,
                              hipStream_t stream) {
    const int*   inputs = (const int*)d_in[0];
    const float* dec    = (const float*)d_in[1];
    const float* enc    = (const float*)d_in[2];
    const float* emb    = (const float*)d_in[3];
    const float* Wih0   = (const float*)d_in[4];
    const float* Whh0   = (const float*)d_in[5];
    const float* bih0   = (const float*)d_in[6];
    const float* bhh0   = (const float*)d_in[7];
    const float* Wih1   = (const float*)d_in[8];
    const float* Whh1   = (const float*)d_in[9];
    const float* bih1   = (const float*)d_in[10];
    const float* bhh1   = (const float*)d_in[11];
    const float* Wout   = (const float*)d_in[12];
    const float* bout   = (const float*)d_in[13];
    float* out = (float*)d_out;

    // choose partial count P (per batch) to fit workspace
    int P = 64;
    while (P > 4) {
        size_t need = ((size_t)P * BATCH * (HDIM + 2) +
                       (EDIM + HDIM) * BATCH + 4u * BH) * sizeof(float);
        if (need <= ws_size) break;
        P >>= 1;
    }
    const int rows = SEQ / P;

    float* w    = (float*)d_ws;
    float* pm   = w;
    float* pl   = pm + (size_t)P * BATCH;
    float* pacc = pl + (size_t)P * BATCH;
    float* xT   = pacc + (size_t)P * BATCH * HDIM;
    float* hT0  = xT + (EDIM + HDIM) * BATCH;
    float* hT1  = hT0 + BH;
    float* h0T  = hT1 + BH;
    float* h1T  = h0T + BH;

    float* h0out = out + (size_t)BATCH * VOCAB;
    float* h1out = h0out + BH;

    attn_partial<<<dim3(P / 4, BATCH), 256, 0, stream>>>(enc, dec, pm, pl, pacc, P, rows);
    attn_combine<<<BATCH, 512, 0, stream>>>(pm, pl, pacc, dec, emb, inputs, xT, hT0, hT1, P);
    gru_cell<<<128, 256, 0, stream>>>(xT, EDIM + HDIM, Wih0, bih0, dec, hT0, Whh0, bhh0, h0out, h0T);
    gru_cell<<<128, 256, 0, stream>>>(h0T, HDIM, Wih1, bih1, dec + BH, hT1, Whh1, bhh1, h1out, h1T);
    vocab_proj<<<(VOCAB + 63) / 64, 512, 0, stream>>>(h1T, Wout, bout, out);
}

// Round 2
// 307.220 us; speedup vs baseline: 1.7151x; 1.7151x over previous
//
#include <hip/hip_runtime.h>
#include <math.h>

#define SEQ   2048
#define BATCH 64
#define HDIM  512
#define EDIM  256
#define VOCAB 50257
#define BH    (BATCH * HDIM)   // 32768

typedef __attribute__((ext_vector_type(4))) float f32x4;
typedef __attribute__((ext_vector_type(8))) short bf16x8;

__device__ __forceinline__ unsigned short f2bf(float x) {
    unsigned int u = __float_as_uint(x);
    u += 0x7fffu + ((u >> 16) & 1u);   // round-to-nearest-even
    return (unsigned short)(u >> 16);
}

// ---------------------------------------------------------------------------
// Kernel 1: flash-style attention partials.
// grid (P/4, BATCH), block 256 (4 waves). Each wave owns one partial p for
// batch b: online softmax over its seq chunk, acc[512] spread 8 floats/lane.
// ---------------------------------------------------------------------------
__global__ __launch_bounds__(256)
void attn_partial(const float* __restrict__ enc, const float* __restrict__ dec,
                  float* __restrict__ pm, float* __restrict__ pl,
                  float* __restrict__ pacc, int P, int rows) {
    const int lane = threadIdx.x & 63;
    const int wave = threadIdx.x >> 6;
    const int p = blockIdx.x * 4 + wave;
    const int b = blockIdx.y;
    const int s0 = p * rows;
    const float scale = 0.044194173824159216f; // 1/sqrt(512)

    const float4* qp = (const float4*)(dec + BH + (size_t)b * HDIM + 8 * lane);
    float4 q0 = qp[0], q1 = qp[1];
    float qa[8] = {q0.x, q0.y, q0.z, q0.w, q1.x, q1.y, q1.z, q1.w};

    float m = -INFINITY, l = 0.f;
    float acc[8] = {0.f, 0.f, 0.f, 0.f, 0.f, 0.f, 0.f, 0.f};

    for (int r = 0; r < rows; r += 4) {
        float va[4][8];
        #pragma unroll
        for (int j = 0; j < 4; ++j) {
            const float4* vp = (const float4*)(enc +
                ((size_t)(s0 + r + j) * BATCH + b) * HDIM + 8 * lane);
            float4 t0 = vp[0], t1 = vp[1];
            va[j][0] = t0.x; va[j][1] = t0.y; va[j][2] = t0.z; va[j][3] = t0.w;
            va[j][4] = t1.x; va[j][5] = t1.y; va[j][6] = t1.z; va[j][7] = t1.w;
        }
        float e[4];
        #pragma unroll
        for (int j = 0; j < 4; ++j) {
            float d = 0.f;
            #pragma unroll
            for (int i = 0; i < 8; ++i) d = fmaf(va[j][i], qa[i], d);
            e[j] = d;
        }
        #pragma unroll
        for (int off = 32; off > 0; off >>= 1) {
            #pragma unroll
            for (int j = 0; j < 4; ++j) e[j] += __shfl_xor(e[j], off, 64);
        }
        #pragma unroll
        for (int j = 0; j < 4; ++j) {
            float ej = e[j] * scale;
            float mn = fmaxf(m, ej);
            float f  = __expf(m - mn);   // exp(-inf)=0 on first row
            float wj = __expf(ej - mn);
            l = l * f + wj;
            #pragma unroll
            for (int i = 0; i < 8; ++i) acc[i] = acc[i] * f + wj * va[j][i];
            m = mn;
        }
    }

    float* pa = pacc + ((size_t)b * P + p) * HDIM + 8 * lane;
    #pragma unroll
    for (int i = 0; i < 8; ++i) pa[i] = acc[i];
    if (lane == 0) { pm[b * P + p] = m; pl[b * P + p] = l; }
}

// ---------------------------------------------------------------------------
// Kernel 2: combine partials -> context; build xT = [emb; ctx] (k-major),
// plus transposed dec_hidden layers hT0/hT1. grid 64 (=b), block 512 (=h).
// ---------------------------------------------------------------------------
__global__ __launch_bounds__(512)
void attn_combine(const float* __restrict__ pm, const float* __restrict__ pl,
                  const float* __restrict__ pacc, const float* __restrict__ dec,
                  const float* __restrict__ emb, const int* __restrict__ inputs,
                  float* __restrict__ xT, float* __restrict__ hT0,
                  float* __restrict__ hT1, int P) {
    __shared__ float s_coef[64];
    __shared__ float s_inv;
    const int b = blockIdx.x;
    const int t = threadIdx.x;

    if (t == 0) {
        float m = -INFINITY;
        for (int p = 0; p < P; ++p) m = fmaxf(m, pm[b * P + p]);
        float denom = 0.f;
        for (int p = 0; p < P; ++p) {
            float c = __expf(pm[b * P + p] - m);
            s_coef[p] = c;
            denom += c * pl[b * P + p];
        }
        s_inv = 1.f / denom;
    }
    __syncthreads();

    float c = 0.f;
    const float* pa = pacc + (size_t)b * P * HDIM + t;
    for (int p = 0; p < P; ++p) c += s_coef[p] * pa[(size_t)p * HDIM];
    float ctx = c * s_inv;

    xT[(EDIM + t) * BATCH + b] = ctx;
    if (t < EDIM) xT[t * BATCH + b] = emb[(size_t)inputs[b] * EDIM + t];
    hT0[t * BATCH + b] = dec[(size_t)b * HDIM + t];
    hT1[t * BATCH + b] = dec[BH + (size_t)b * HDIM + t];
}

// ---------------------------------------------------------------------------
// Kernel 3: GRU cell. grid 128, block 256; wave-uniform h (scalar W loads),
// lane = batch (coalesced xT/hprevT loads). Writes h_out row-major +
// transposed + (optionally) bf16 row-major for the MFMA vocab projection.
// ---------------------------------------------------------------------------
__global__ __launch_bounds__(256)
void gru_cell(const float* __restrict__ xT, int K1,
              const float* __restrict__ Wih, const float* __restrict__ bih,
              const float* __restrict__ hprev, const float* __restrict__ hprevT,
              const float* __restrict__ Whh, const float* __restrict__ bhh,
              float* __restrict__ hout, float* __restrict__ houtT,
              unsigned short* __restrict__ houtBf) {
    const int lane = threadIdx.x & 63;
    const int h = blockIdx.x * 4 + (threadIdx.x >> 6);

    const float* wr = Wih + (size_t)h * K1;
    const float* wz = Wih + (size_t)(HDIM + h) * K1;
    const float* wn = Wih + (size_t)(2 * HDIM + h) * K1;
    float ar = 0.f, az = 0.f, an = 0.f;
    #pragma unroll 4
    for (int k = 0; k < K1; ++k) {
        float xv = xT[k * BATCH + lane];
        ar = fmaf(wr[k], xv, ar);
        az = fmaf(wz[k], xv, az);
        an = fmaf(wn[k], xv, an);
    }

    const float* ur = Whh + (size_t)h * HDIM;
    const float* uz = Whh + (size_t)(HDIM + h) * HDIM;
    const float* un = Whh + (size_t)(2 * HDIM + h) * HDIM;
    float hr = 0.f, hz = 0.f, hn = 0.f;
    #pragma unroll 4
    for (int k = 0; k < HDIM; ++k) {
        float hv = hprevT[k * BATCH + lane];
        hr = fmaf(ur[k], hv, hr);
        hz = fmaf(uz[k], hv, hz);
        hn = fmaf(un[k], hv, hn);
    }

    float gr  = ar + bih[h]            + hr + bhh[h];
    float gz  = az + bih[HDIM + h]     + hz + bhh[HDIM + h];
    float gin = an + bih[2 * HDIM + h];
    float ghn = hn + bhh[2 * HDIM + h];
    float r = 1.f / (1.f + __expf(-gr));
    float z = 1.f / (1.f + __expf(-gz));
    float n = tanhf(gin + r * ghn);
    float hp = hprev[(size_t)lane * HDIM + h];
    float hnew = (1.f - z) * n + z * hp;

    hout[(size_t)lane * HDIM + h] = hnew;
    houtT[(size_t)h * BATCH + lane] = hnew;
    if (houtBf) houtBf[(size_t)lane * HDIM + h] = f2bf(hnew);
}

// ---------------------------------------------------------------------------
// Kernel 4: vocab projection via MFMA.  logits[64 x 50257] = h1 @ W^T + b.
// W is [V][512] row-major == B^T layout. Per wave: 16-vocab N-tile x all 64
// batches (4 M-tiles). Per K=32 step: 2x dwordx4 of W (fp32->bf16 RNE in
// register), 4x 16B A-frag loads of bf16 h1 (64KB, L1/L2-hot), 4 MFMA.
// No LDS, no barriers -> pure HBM stream of W.
// ---------------------------------------------------------------------------
__global__ __launch_bounds__(256)
void vocab_proj_mfma(const unsigned short* __restrict__ h1bf,
                     const float* __restrict__ Wout,
                     const float* __restrict__ bout,
                     float* __restrict__ logits) {
    const int NT = (VOCAB + 15) / 16;          // 3142 N-tiles
    const int lane = threadIdx.x & 63;
    const int nt = blockIdx.x * 4 + (threadIdx.x >> 6);
    if (nt >= NT) return;

    const int v0 = nt * 16;
    const int nn = lane & 15;                   // fragment col (vocab)
    const int v  = v0 + nn;
    const int vclamp = min(v, VOCAB - 1);
    const int koff = (lane >> 4) * 8;           // fragment k base

    const float* wrow = Wout + (size_t)vclamp * HDIM + koff;
    const unsigned short* arow = h1bf + nn * HDIM + koff;

    f32x4 acc0 = {0,0,0,0}, acc1 = {0,0,0,0}, acc2 = {0,0,0,0}, acc3 = {0,0,0,0};

    #pragma unroll 4
    for (int ks = 0; ks < 16; ++ks) {
        float4 b0 = *(const float4*)(wrow + 32 * ks);
        float4 b1 = *(const float4*)(wrow + 32 * ks + 4);
        bf16x8 bf;
        bf[0] = (short)f2bf(b0.x); bf[1] = (short)f2bf(b0.y);
        bf[2] = (short)f2bf(b0.z); bf[3] = (short)f2bf(b0.w);
        bf[4] = (short)f2bf(b1.x); bf[5] = (short)f2bf(b1.y);
        bf[6] = (short)f2bf(b1.z); bf[7] = (short)f2bf(b1.w);

        bf16x8 a0 = *(const bf16x8*)(arow + 32 * ks);
        bf16x8 a1 = *(const bf16x8*)(arow + 16 * HDIM + 32 * ks);
        bf16x8 a2 = *(const bf16x8*)(arow + 32 * HDIM + 32 * ks);
        bf16x8 a3 = *(const bf16x8*)(arow + 48 * HDIM + 32 * ks);

        acc0 = __builtin_amdgcn_mfma_f32_16x16x32_bf16(a0, bf, acc0, 0, 0, 0);
        acc1 = __builtin_amdgcn_mfma_f32_16x16x32_bf16(a1, bf, acc1, 0, 0, 0);
        acc2 = __builtin_amdgcn_mfma_f32_16x16x32_bf16(a2, bf, acc2, 0, 0, 0);
        acc3 = __builtin_amdgcn_mfma_f32_16x16x32_bf16(a3, bf, acc3, 0, 0, 0);
    }

    if (v < VOCAB) {
        const float bias = bout[v];
        const int b0 = (lane >> 4) * 4;          // fragment row (batch)
        #pragma unroll
        for (int r = 0; r < 4; ++r) {
            logits[(size_t)(b0 + r)      * VOCAB + v] = acc0[r] + bias;
            logits[(size_t)(b0 + r + 16) * VOCAB + v] = acc1[r] + bias;
            logits[(size_t)(b0 + r + 32) * VOCAB + v] = acc2[r] + bias;
            logits[(size_t)(b0 + r + 48) * VOCAB + v] = acc3[r] + bias;
        }
    }
}

// ---------------------------------------------------------------------------
extern "C" void kernel_launch(void* const* d_in, const int* in_sizes, int n_in,
                              void* d_out, int out_size, void* d_ws, size_t ws_size,
                              hipStream_t stream) {
    const int*   inputs = (const int*)d_in[0];
    const float* dec    = (const float*)d_in[1];
    const float* enc    = (const float*)d_in[2];
    const float* emb    = (const float*)d_in[3];
    const float* Wih0   = (const float*)d_in[4];
    const float* Whh0   = (const float*)d_in[5];
    const float* bih0   = (const float*)d_in[6];
    const float* bhh0   = (const float*)d_in[7];
    const float* Wih1   = (const float*)d_in[8];
    const float* Whh1   = (const float*)d_in[9];
    const float* bih1   = (const float*)d_in[10];
    const float* bhh1   = (const float*)d_in[11];
    const float* Wout   = (const float*)d_in[12];
    const float* bout   = (const float*)d_in[13];
    float* out = (float*)d_out;

    // choose partial count P (per batch) to fit workspace
    int P = 64;
    while (P > 4) {
        size_t need = ((size_t)P * BATCH * (HDIM + 2) +
                       (EDIM + HDIM) * BATCH + 4u * BH) * sizeof(float)
                      + 2u * BH; // bf16 h1
        if (need <= ws_size) break;
        P >>= 1;
    }
    const int rows = SEQ / P;

    float* w    = (float*)d_ws;
    float* pm   = w;
    float* pl   = pm + (size_t)P * BATCH;
    float* pacc = pl + (size_t)P * BATCH;
    float* xT   = pacc + (size_t)P * BATCH * HDIM;
    float* hT0  = xT + (EDIM + HDIM) * BATCH;
    float* hT1  = hT0 + BH;
    float* h0T  = hT1 + BH;
    float* h1T  = h0T + BH;
    unsigned short* h1bf = (unsigned short*)(h1T + BH);

    float* h0out = out + (size_t)BATCH * VOCAB;
    float* h1out = h0out + BH;

    attn_partial<<<dim3(P / 4, BATCH), 256, 0, stream>>>(enc, dec, pm, pl, pacc, P, rows);
    attn_combine<<<BATCH, 512, 0, stream>>>(pm, pl, pacc, dec, emb, inputs, xT, hT0, hT1, P);
    gru_cell<<<128, 256, 0, stream>>>(xT, EDIM + HDIM, Wih0, bih0, dec, hT0, Whh0, bhh0, h0out, h0T, (unsigned short*)0);
    gru_cell<<<128, 256, 0, stream>>>(h0T, HDIM, Wih1, bih1, dec + BH, hT1, Whh1, bhh1, h1out, h1T, h1bf);

    const int NT = (VOCAB + 15) / 16;
    vocab_proj_mfma<<<(NT + 3) / 4, 256, 0, stream>>>(h1bf, Wout, bout, out);
}

// Round 3
// 273.146 us; speedup vs baseline: 1.9291x; 1.1247x over previous
//
#include <hip/hip_runtime.h>
#include <math.h>

#define SEQ   2048
#define BATCH 64
#define HDIM  512
#define EDIM  256
#define VOCAB 50257
#define BH    (BATCH * HDIM)   // 32768

typedef __attribute__((ext_vector_type(4))) float f32x4;
typedef __attribute__((ext_vector_type(8))) short bf16x8;

__device__ __forceinline__ unsigned short f2bf(float x) {
    unsigned int u = __float_as_uint(x);
    u += 0x7fffu + ((u >> 16) & 1u);   // round-to-nearest-even
    return (unsigned short)(u >> 16);
}

__device__ __forceinline__ bf16x8 cvt8(const float* p) {
    float4 a = *(const float4*)p;
    float4 b = *(const float4*)(p + 4);
    bf16x8 r;
    r[0] = (short)f2bf(a.x); r[1] = (short)f2bf(a.y);
    r[2] = (short)f2bf(a.z); r[3] = (short)f2bf(a.w);
    r[4] = (short)f2bf(b.x); r[5] = (short)f2bf(b.y);
    r[6] = (short)f2bf(b.z); r[7] = (short)f2bf(b.w);
    return r;
}

// ---------------------------------------------------------------------------
// Kernel 1: flash-style attention partials (unchanged — BW-bound ~45us).
// ---------------------------------------------------------------------------
__global__ __launch_bounds__(256)
void attn_partial(const float* __restrict__ enc, const float* __restrict__ dec,
                  float* __restrict__ pm, float* __restrict__ pl,
                  float* __restrict__ pacc, int P, int rows) {
    const int lane = threadIdx.x & 63;
    const int wave = threadIdx.x >> 6;
    const int p = blockIdx.x * 4 + wave;
    const int b = blockIdx.y;
    const int s0 = p * rows;
    const float scale = 0.044194173824159216f; // 1/sqrt(512)

    const float4* qp = (const float4*)(dec + BH + (size_t)b * HDIM + 8 * lane);
    float4 q0 = qp[0], q1 = qp[1];
    float qa[8] = {q0.x, q0.y, q0.z, q0.w, q1.x, q1.y, q1.z, q1.w};

    float m = -INFINITY, l = 0.f;
    float acc[8] = {0.f, 0.f, 0.f, 0.f, 0.f, 0.f, 0.f, 0.f};

    for (int r = 0; r < rows; r += 4) {
        float va[4][8];
        #pragma unroll
        for (int j = 0; j < 4; ++j) {
            const float4* vp = (const float4*)(enc +
                ((size_t)(s0 + r + j) * BATCH + b) * HDIM + 8 * lane);
            float4 t0 = vp[0], t1 = vp[1];
            va[j][0] = t0.x; va[j][1] = t0.y; va[j][2] = t0.z; va[j][3] = t0.w;
            va[j][4] = t1.x; va[j][5] = t1.y; va[j][6] = t1.z; va[j][7] = t1.w;
        }
        float e[4];
        #pragma unroll
        for (int j = 0; j < 4; ++j) {
            float d = 0.f;
            #pragma unroll
            for (int i = 0; i < 8; ++i) d = fmaf(va[j][i], qa[i], d);
            e[j] = d;
        }
        #pragma unroll
        for (int off = 32; off > 0; off >>= 1) {
            #pragma unroll
            for (int j = 0; j < 4; ++j) e[j] += __shfl_xor(e[j], off, 64);
        }
        #pragma unroll
        for (int j = 0; j < 4; ++j) {
            float ej = e[j] * scale;
            float mn = fmaxf(m, ej);
            float f  = __expf(m - mn);
            float wj = __expf(ej - mn);
            l = l * f + wj;
            #pragma unroll
            for (int i = 0; i < 8; ++i) acc[i] = acc[i] * f + wj * va[j][i];
            m = mn;
        }
    }

    float* pa = pacc + ((size_t)b * P + p) * HDIM + 8 * lane;
    #pragma unroll
    for (int i = 0; i < 8; ++i) pa[i] = acc[i];
    if (lane == 0) { pm[b * P + p] = m; pl[b * P + p] = l; }
}

// ---------------------------------------------------------------------------
// Kernel 2: combine partials -> context. Now emits bf16 ROW-MAJOR activations
// for the MFMA GRU: xbf = [emb | ctx] (64x768), dec0bf/dec1bf (64x512).
// grid 64 (=b), block 512 (=h).
// ---------------------------------------------------------------------------
__global__ __launch_bounds__(512)
void attn_combine(const float* __restrict__ pm, const float* __restrict__ pl,
                  const float* __restrict__ pacc, const float* __restrict__ dec,
                  const float* __restrict__ emb, const int* __restrict__ inputs,
                  unsigned short* __restrict__ xbf,
                  unsigned short* __restrict__ d0bf,
                  unsigned short* __restrict__ d1bf, int P) {
    __shared__ float s_coef[64];
    __shared__ float s_inv;
    const int b = blockIdx.x;
    const int t = threadIdx.x;

    if (t == 0) {
        float m = -INFINITY;
        for (int p = 0; p < P; ++p) m = fmaxf(m, pm[b * P + p]);
        float denom = 0.f;
        for (int p = 0; p < P; ++p) {
            float c = __expf(pm[b * P + p] - m);
            s_coef[p] = c;
            denom += c * pl[b * P + p];
        }
        s_inv = 1.f / denom;
    }
    __syncthreads();

    float c = 0.f;
    const float* pa = pacc + (size_t)b * P * HDIM + t;
    for (int p = 0; p < P; ++p) c += s_coef[p] * pa[(size_t)p * HDIM];
    float ctx = c * s_inv;

    xbf[(size_t)b * (EDIM + HDIM) + EDIM + t] = f2bf(ctx);
    if (t < EDIM)
        xbf[(size_t)b * (EDIM + HDIM) + t] = f2bf(emb[(size_t)inputs[b] * EDIM + t]);
    d0bf[(size_t)b * HDIM + t] = f2bf(dec[(size_t)b * HDIM + t]);
    d1bf[(size_t)b * HDIM + t] = f2bf(dec[BH + (size_t)b * HDIM + t]);
}

// ---------------------------------------------------------------------------
// Kernel 3: GRU cell via MFMA (same verified fragment mapping as vocab).
// One wave per 16-gate column tile (32 tiles -> grid 8 x 256). Six acc sets:
// {r,z,n} x {ih,hh}, 4 M-tiles (batch) each. Weights fp32 [3H][K] row-major
// = B^T layout, cvt to bf16 in-register. Gate math fused; writes fp32 h to
// d_out (new_hidden[layer]) + bf16 row-major for the next consumer.
// ---------------------------------------------------------------------------
template<int K1>
__global__ __launch_bounds__(256)
void gru_mfma(const unsigned short* __restrict__ xbf,
              const float* __restrict__ Wih, const float* __restrict__ bih,
              const unsigned short* __restrict__ hbf,
              const float* __restrict__ hprev,
              const float* __restrict__ Whh, const float* __restrict__ bhh,
              float* __restrict__ hout, unsigned short* __restrict__ houtBf) {
    const int lane = threadIdx.x & 63;
    const int gt = blockIdx.x * 4 + (threadIdx.x >> 6);  // 0..31
    const int nn = lane & 15;
    const int g = gt * 16 + nn;                          // gate column
    const int koff = (lane >> 4) * 8;

    f32x4 aIR[4], aIZ[4], aIN[4], aHR[4], aHZ[4], aHN[4];
    #pragma unroll
    for (int mt = 0; mt < 4; ++mt) {
        aIR[mt] = (f32x4){0,0,0,0}; aIZ[mt] = (f32x4){0,0,0,0};
        aIN[mt] = (f32x4){0,0,0,0}; aHR[mt] = (f32x4){0,0,0,0};
        aHZ[mt] = (f32x4){0,0,0,0}; aHN[mt] = (f32x4){0,0,0,0};
    }

    // ---- ih gemm: A = xbf [64][K1], B^T = Wih rows {g, 512+g, 1024+g} ----
    {
        const float* wR = Wih + (size_t)g * K1 + koff;
        const float* wZ = Wih + (size_t)(HDIM + g) * K1 + koff;
        const float* wN = Wih + (size_t)(2 * HDIM + g) * K1 + koff;
        const unsigned short* arow = xbf + (size_t)nn * K1 + koff;
        #pragma unroll 2
        for (int ks = 0; ks < K1 / 32; ++ks) {
            bf16x8 bR = cvt8(wR + 32 * ks);
            bf16x8 bZ = cvt8(wZ + 32 * ks);
            bf16x8 bN = cvt8(wN + 32 * ks);
            #pragma unroll
            for (int mt = 0; mt < 4; ++mt) {
                bf16x8 a = *(const bf16x8*)(arow + (size_t)mt * 16 * K1 + 32 * ks);
                aIR[mt] = __builtin_amdgcn_mfma_f32_16x16x32_bf16(a, bR, aIR[mt], 0, 0, 0);
                aIZ[mt] = __builtin_amdgcn_mfma_f32_16x16x32_bf16(a, bZ, aIZ[mt], 0, 0, 0);
                aIN[mt] = __builtin_amdgcn_mfma_f32_16x16x32_bf16(a, bN, aIN[mt], 0, 0, 0);
            }
        }
    }
    // ---- hh gemm: A = hbf [64][512], B^T = Whh rows ----
    {
        const float* uR = Whh + (size_t)g * HDIM + koff;
        const float* uZ = Whh + (size_t)(HDIM + g) * HDIM + koff;
        const float* uN = Whh + (size_t)(2 * HDIM + g) * HDIM + koff;
        const unsigned short* arow = hbf + (size_t)nn * HDIM + koff;
        #pragma unroll 2
        for (int ks = 0; ks < HDIM / 32; ++ks) {
            bf16x8 bR = cvt8(uR + 32 * ks);
            bf16x8 bZ = cvt8(uZ + 32 * ks);
            bf16x8 bN = cvt8(uN + 32 * ks);
            #pragma unroll
            for (int mt = 0; mt < 4; ++mt) {
                bf16x8 a = *(const bf16x8*)(arow + (size_t)mt * 16 * HDIM + 32 * ks);
                aHR[mt] = __builtin_amdgcn_mfma_f32_16x16x32_bf16(a, bR, aHR[mt], 0, 0, 0);
                aHZ[mt] = __builtin_amdgcn_mfma_f32_16x16x32_bf16(a, bZ, aHZ[mt], 0, 0, 0);
                aHN[mt] = __builtin_amdgcn_mfma_f32_16x16x32_bf16(a, bN, aHN[mt], 0, 0, 0);
            }
        }
    }

    // ---- fused gate math + writeback ----
    const float bIR = bih[g], bIZ = bih[HDIM + g], bIN = bih[2 * HDIM + g];
    const float bHR = bhh[g], bHZ = bhh[HDIM + g], bHN = bhh[2 * HDIM + g];
    const int brow = (lane >> 4) * 4;
    #pragma unroll
    for (int mt = 0; mt < 4; ++mt) {
        #pragma unroll
        for (int j = 0; j < 4; ++j) {
            const int b = mt * 16 + brow + j;
            float r = 1.f / (1.f + __expf(-(aIR[mt][j] + bIR + aHR[mt][j] + bHR)));
            float z = 1.f / (1.f + __expf(-(aIZ[mt][j] + bIZ + aHZ[mt][j] + bHZ)));
            float n = tanhf(aIN[mt][j] + bIN + r * (aHN[mt][j] + bHN));
            float hp = hprev[(size_t)b * HDIM + g];
            float hn = (1.f - z) * n + z * hp;
            hout[(size_t)b * HDIM + g] = hn;
            houtBf[(size_t)b * HDIM + g] = f2bf(hn);
        }
    }
}

// ---------------------------------------------------------------------------
// Kernel 4: vocab projection via MFMA (unchanged).
// ---------------------------------------------------------------------------
__global__ __launch_bounds__(256)
void vocab_proj_mfma(const unsigned short* __restrict__ h1bf,
                     const float* __restrict__ Wout,
                     const float* __restrict__ bout,
                     float* __restrict__ logits) {
    const int NT = (VOCAB + 15) / 16;
    const int lane = threadIdx.x & 63;
    const int nt = blockIdx.x * 4 + (threadIdx.x >> 6);
    if (nt >= NT) return;

    const int v0 = nt * 16;
    const int nn = lane & 15;
    const int v  = v0 + nn;
    const int vclamp = min(v, VOCAB - 1);
    const int koff = (lane >> 4) * 8;

    const float* wrow = Wout + (size_t)vclamp * HDIM + koff;
    const unsigned short* arow = h1bf + nn * HDIM + koff;

    f32x4 acc0 = {0,0,0,0}, acc1 = {0,0,0,0}, acc2 = {0,0,0,0}, acc3 = {0,0,0,0};

    #pragma unroll 4
    for (int ks = 0; ks < 16; ++ks) {
        bf16x8 bf = cvt8(wrow + 32 * ks);
        bf16x8 a0 = *(const bf16x8*)(arow + 32 * ks);
        bf16x8 a1 = *(const bf16x8*)(arow + 16 * HDIM + 32 * ks);
        bf16x8 a2 = *(const bf16x8*)(arow + 32 * HDIM + 32 * ks);
        bf16x8 a3 = *(const bf16x8*)(arow + 48 * HDIM + 32 * ks);

        acc0 = __builtin_amdgcn_mfma_f32_16x16x32_bf16(a0, bf, acc0, 0, 0, 0);
        acc1 = __builtin_amdgcn_mfma_f32_16x16x32_bf16(a1, bf, acc1, 0, 0, 0);
        acc2 = __builtin_amdgcn_mfma_f32_16x16x32_bf16(a2, bf, acc2, 0, 0, 0);
        acc3 = __builtin_amdgcn_mfma_f32_16x16x32_bf16(a3, bf, acc3, 0, 0, 0);
    }

    if (v < VOCAB) {
        const float bias = bout[v];
        const int b0 = (lane >> 4) * 4;
        #pragma unroll
        for (int r = 0; r < 4; ++r) {
            logits[(size_t)(b0 + r)      * VOCAB + v] = acc0[r] + bias;
            logits[(size_t)(b0 + r + 16) * VOCAB + v] = acc1[r] + bias;
            logits[(size_t)(b0 + r + 32) * VOCAB + v] = acc2[r] + bias;
            logits[(size_t)(b0 + r + 48) * VOCAB + v] = acc3[r] + bias;
        }
    }
}

// ---------------------------------------------------------------------------
extern "C" void kernel_launch(void* const* d_in, const int* in_sizes, int n_in,
                              void* d_out, int out_size, void* d_ws, size_t ws_size,
                              hipStream_t stream) {
    const int*   inputs = (const int*)d_in[0];
    const float* dec    = (const float*)d_in[1];
    const float* enc    = (const float*)d_in[2];
    const float* emb    = (const float*)d_in[3];
    const float* Wih0   = (const float*)d_in[4];
    const float* Whh0   = (const float*)d_in[5];
    const float* bih0   = (const float*)d_in[6];
    const float* bhh0   = (const float*)d_in[7];
    const float* Wih1   = (const float*)d_in[8];
    const float* Whh1   = (const float*)d_in[9];
    const float* bih1   = (const float*)d_in[10];
    const float* bhh1   = (const float*)d_in[11];
    const float* Wout   = (const float*)d_in[12];
    const float* bout   = (const float*)d_in[13];
    float* out = (float*)d_out;

    int P = 64;
    while (P > 4) {
        size_t need = ((size_t)P * BATCH * (HDIM + 2)) * sizeof(float)
                      + 2u * (BATCH * (EDIM + HDIM) + 4u * BH);
        if (need <= ws_size) break;
        P >>= 1;
    }
    const int rows = SEQ / P;

    float* w    = (float*)d_ws;
    float* pm   = w;
    float* pl   = pm + (size_t)P * BATCH;
    float* pacc = pl + (size_t)P * BATCH;
    unsigned short* xbf  = (unsigned short*)(pacc + (size_t)P * BATCH * HDIM);
    unsigned short* d0bf = xbf + (size_t)BATCH * (EDIM + HDIM);
    unsigned short* d1bf = d0bf + BH;
    unsigned short* h0bf = d1bf + BH;
    unsigned short* h1bf = h0bf + BH;

    float* h0out = out + (size_t)BATCH * VOCAB;   // new_hidden[0]
    float* h1out = h0out + BH;                    // new_hidden[1]

    attn_partial<<<dim3(P / 4, BATCH), 256, 0, stream>>>(enc, dec, pm, pl, pacc, P, rows);
    attn_combine<<<BATCH, 512, 0, stream>>>(pm, pl, pacc, dec, emb, inputs, xbf, d0bf, d1bf, P);
    gru_mfma<EDIM + HDIM><<<8, 256, 0, stream>>>(xbf, Wih0, bih0, d0bf, dec, Whh0, bhh0, h0out, h0bf);
    gru_mfma<HDIM><<<8, 256, 0, stream>>>(h0bf, Wih1, bih1, d1bf, dec + BH, Whh1, bhh1, h1out, h1bf);

    const int NT = (VOCAB + 15) / 16;
    vocab_proj_mfma<<<(NT + 3) / 4, 256, 0, stream>>>(h1bf, Wout, bout, out);
}

// Round 4
// 142.840 us; speedup vs baseline: 3.6889x; 1.9123x over previous
//
#include <hip/hip_runtime.h>
#include <math.h>

#define SEQ   2048
#define BATCH 64
#define HDIM  512
#define EDIM  256
#define VOCAB 50257
#define BH    (BATCH * HDIM)   // 32768
#define G3    (3 * HDIM)       // 1536
#define NCOL  (2 * G3)         // 3072 combined gate columns (ih | hh)

typedef __attribute__((ext_vector_type(4))) float f32x4;
typedef __attribute__((ext_vector_type(8))) short bf16x8;

__device__ __forceinline__ unsigned short f2bf(float x) {
    unsigned int u = __float_as_uint(x);
    u += 0x7fffu + ((u >> 16) & 1u);   // round-to-nearest-even
    return (unsigned short)(u >> 16);
}

__device__ __forceinline__ bf16x8 pack8(float4 a, float4 b) {
    bf16x8 r;
    r[0] = (short)f2bf(a.x); r[1] = (short)f2bf(a.y);
    r[2] = (short)f2bf(a.z); r[3] = (short)f2bf(a.w);
    r[4] = (short)f2bf(b.x); r[5] = (short)f2bf(b.y);
    r[6] = (short)f2bf(b.z); r[7] = (short)f2bf(b.w);
    return r;
}

__device__ __forceinline__ bf16x8 cvt8(const float* p) {
    return pack8(*(const float4*)p, *(const float4*)(p + 4));
}

// ---------------------------------------------------------------------------
// Kernel 1: flash-style attention partials. P=128 -> grid (32,64) = 2048
// blocks (up to 32 waves/CU). Batched 4-row online-softmax update (one
// rescale per 4 rows, shorter serial chain).
// ---------------------------------------------------------------------------
__global__ __launch_bounds__(256)
void attn_partial(const float* __restrict__ enc, const float* __restrict__ dec,
                  float* __restrict__ pm, float* __restrict__ pl,
                  float* __restrict__ pacc, int P, int rows) {
    const int lane = threadIdx.x & 63;
    const int wave = threadIdx.x >> 6;
    const int p = blockIdx.x * 4 + wave;
    const int b = blockIdx.y;
    const int s0 = p * rows;
    const float scale = 0.044194173824159216f; // 1/sqrt(512)

    const float4* qp = (const float4*)(dec + BH + (size_t)b * HDIM + 8 * lane);
    float4 q0 = qp[0], q1 = qp[1];
    float qa[8] = {q0.x, q0.y, q0.z, q0.w, q1.x, q1.y, q1.z, q1.w};

    float m = -INFINITY, l = 0.f;
    float acc[8] = {0.f, 0.f, 0.f, 0.f, 0.f, 0.f, 0.f, 0.f};

    #pragma unroll 2
    for (int r = 0; r < rows; r += 4) {
        float va[4][8];
        #pragma unroll
        for (int j = 0; j < 4; ++j) {
            const float4* vp = (const float4*)(enc +
                ((size_t)(s0 + r + j) * BATCH + b) * HDIM + 8 * lane);
            float4 t0 = vp[0], t1 = vp[1];
            va[j][0] = t0.x; va[j][1] = t0.y; va[j][2] = t0.z; va[j][3] = t0.w;
            va[j][4] = t1.x; va[j][5] = t1.y; va[j][6] = t1.z; va[j][7] = t1.w;
        }
        float e[4];
        #pragma unroll
        for (int j = 0; j < 4; ++j) {
            float d = 0.f;
            #pragma unroll
            for (int i = 0; i < 8; ++i) d = fmaf(va[j][i], qa[i], d);
            e[j] = d;
        }
        #pragma unroll
        for (int off = 32; off > 0; off >>= 1) {
            #pragma unroll
            for (int j = 0; j < 4; ++j) e[j] += __shfl_xor(e[j], off, 64);
        }
        #pragma unroll
        for (int j = 0; j < 4; ++j) e[j] *= scale;
        float m4 = fmaxf(fmaxf(e[0], e[1]), fmaxf(e[2], e[3]));
        float em = fmaxf(m, m4);
        float f  = __expf(m - em);              // exp(-inf)=0 on first iter
        float w0 = __expf(e[0] - em), w1 = __expf(e[1] - em);
        float w2 = __expf(e[2] - em), w3 = __expf(e[3] - em);
        l = l * f + (w0 + w1 + w2 + w3);
        #pragma unroll
        for (int i = 0; i < 8; ++i) {
            float a = acc[i] * f;
            a = fmaf(w0, va[0][i], a);
            a = fmaf(w1, va[1][i], a);
            a = fmaf(w2, va[2][i], a);
            acc[i] = fmaf(w3, va[3][i], a);
        }
        m = em;
    }

    float* pa = pacc + ((size_t)b * P + p) * HDIM + 8 * lane;
    #pragma unroll
    for (int i = 0; i < 8; ++i) pa[i] = acc[i];
    if (lane == 0) { pm[b * P + p] = m; pl[b * P + p] = l; }
}

// ---------------------------------------------------------------------------
// Kernel 2: combine partials -> context (bf16 row-major activations out).
// Wave-parallel partial-softmax combine (P<=128). grid 64, block 512.
// ---------------------------------------------------------------------------
__global__ __launch_bounds__(512)
void attn_combine(const float* __restrict__ pm, const float* __restrict__ pl,
                  const float* __restrict__ pacc, const float* __restrict__ dec,
                  const float* __restrict__ emb, const int* __restrict__ inputs,
                  unsigned short* __restrict__ xbf,
                  unsigned short* __restrict__ d0bf,
                  unsigned short* __restrict__ d1bf, int P) {
    __shared__ float s_coef[128];
    __shared__ float s_inv;
    const int b = blockIdx.x;
    const int t = threadIdx.x;

    if (t < 64) {
        float mloc = -INFINITY;
        for (int p = t; p < P; p += 64) mloc = fmaxf(mloc, pm[b * P + p]);
        #pragma unroll
        for (int off = 32; off > 0; off >>= 1) mloc = fmaxf(mloc, __shfl_xor(mloc, off, 64));
        float d = 0.f;
        for (int p = t; p < P; p += 64) {
            float c = __expf(pm[b * P + p] - mloc);
            s_coef[p] = c;
            d = fmaf(c, pl[b * P + p], d);
        }
        #pragma unroll
        for (int off = 32; off > 0; off >>= 1) d += __shfl_xor(d, off, 64);
        if (t == 0) s_inv = 1.f / d;
    }
    __syncthreads();

    float c = 0.f;
    const float* pa = pacc + (size_t)b * P * HDIM + t;
    #pragma unroll 4
    for (int p = 0; p < P; ++p) c = fmaf(s_coef[p], pa[(size_t)p * HDIM], c);
    float ctx = c * s_inv;

    xbf[(size_t)b * (EDIM + HDIM) + EDIM + t] = f2bf(ctx);
    if (t < EDIM)
        xbf[(size_t)b * (EDIM + HDIM) + t] = f2bf(emb[(size_t)inputs[b] * EDIM + t]);
    d0bf[(size_t)b * HDIM + t] = f2bf(dec[(size_t)b * HDIM + t]);
    d1bf[(size_t)b * HDIM + t] = f2bf(dec[BH + (size_t)b * HDIM + t]);
}

// ---------------------------------------------------------------------------
// Kernel 3a: GRU gemms, flattened. 3072 combined columns (1536 ih | 1536 hh),
// 192 N-tiles x KS=2 K-chunks -> grid (48,2), 4 waves/block. Writes fp32
// partial pre-activations part[kc][col][64].
// ---------------------------------------------------------------------------
template<int K1>
__global__ __launch_bounds__(256)
void gru_gemm(const unsigned short* __restrict__ Aih,  // [64][K1]
              const unsigned short* __restrict__ Ahh,  // [64][512]
              const float* __restrict__ Wih,           // [1536][K1]
              const float* __restrict__ Whh,           // [1536][512]
              float* __restrict__ part) {              // [2][3072][64]
    const int lane = threadIdx.x & 63;
    const int nt = blockIdx.x * 4 + (threadIdx.x >> 6);  // 0..191
    const int kc = blockIdx.y;                           // 0..1
    const int nn = lane & 15;
    const int koff = (lane >> 4) * 8;

    const bool ih = nt < 96;
    const int col16 = ih ? nt : nt - 96;
    const int g = col16 * 16 + nn;                       // W row 0..1535
    const int K = ih ? K1 : HDIM;
    const int kchunk = K >> 1;
    const int k0 = kc * kchunk;

    const float* wrow = (ih ? Wih : Whh) + (size_t)g * K + k0 + koff;
    const unsigned short* arow = (ih ? Aih : Ahh) + (size_t)nn * K + k0 + koff;

    f32x4 acc[4];
    #pragma unroll
    for (int mt = 0; mt < 4; ++mt) acc[mt] = (f32x4){0, 0, 0, 0};

    const int nks = kchunk >> 5;     // 12 (ih,K=768) / 8 (K=512)
    #pragma unroll 4
    for (int ks = 0; ks < nks; ++ks) {
        bf16x8 bf = cvt8(wrow + 32 * ks);
        #pragma unroll
        for (int mt = 0; mt < 4; ++mt) {
            bf16x8 a = *(const bf16x8*)(arow + (size_t)mt * 16 * K + 32 * ks);
            acc[mt] = __builtin_amdgcn_mfma_f32_16x16x32_bf16(a, bf, acc[mt], 0, 0, 0);
        }
    }

    const int col = col16 * 16 + nn + (ih ? 0 : G3);
    float* pp = part + ((size_t)kc * NCOL + col) * 64 + (lane >> 4) * 4;
    #pragma unroll
    for (int mt = 0; mt < 4; ++mt)
        *(f32x4*)(pp + mt * 16) = acc[mt];
}

// ---------------------------------------------------------------------------
// Kernel 3b: GRU gate math. One thread per (b,h). grid 128, block 256.
// ---------------------------------------------------------------------------
__global__ __launch_bounds__(256)
void gru_gate(const float* __restrict__ part,          // [2][3072][64]
              const float* __restrict__ hprev,         // [64][512] fp32
              const float* __restrict__ bih, const float* __restrict__ bhh,
              float* __restrict__ hout, unsigned short* __restrict__ houtBf) {
    const int gidx = blockIdx.x * 256 + threadIdx.x;    // 0..32767
    const int b = gidx & 63;
    const int h = gidx >> 6;

    #define PRD(c) (part[(size_t)(c) * 64 + b] + part[(size_t)((c) + NCOL) * 64 + b])
    float ir = PRD(h),            hr = PRD(G3 + h);
    float iz = PRD(HDIM + h),     hz = PRD(G3 + HDIM + h);
    float in_ = PRD(2 * HDIM + h), hn = PRD(G3 + 2 * HDIM + h);
    #undef PRD

    float r = 1.f / (1.f + __expf(-(ir + bih[h] + hr + bhh[h])));
    float z = 1.f / (1.f + __expf(-(iz + bih[HDIM + h] + hz + bhh[HDIM + h])));
    float n = tanhf(in_ + bih[2 * HDIM + h] + r * (hn + bhh[2 * HDIM + h]));
    float hp = hprev[(size_t)b * HDIM + h];
    float hnew = (1.f - z) * n + z * hp;

    hout[(size_t)b * HDIM + h] = hnew;
    houtBf[(size_t)b * HDIM + h] = f2bf(hnew);
}

// ---------------------------------------------------------------------------
// Kernel 4: vocab projection via MFMA. 2 N-tiles (32 vocab cols) per wave,
// depth-2 register prefetch of W to keep >=4KB/wave in flight; A (h1bf)
// shared across both tiles.
// ---------------------------------------------------------------------------
__global__ __launch_bounds__(256)
void vocab_proj_mfma(const unsigned short* __restrict__ h1bf,
                     const float* __restrict__ Wout,
                     const float* __restrict__ bout,
                     float* __restrict__ logits) {
    const int NPAIR = (VOCAB + 31) / 32;                // 1571
    const int lane = threadIdx.x & 63;
    const int w = blockIdx.x * 4 + (threadIdx.x >> 6);
    if (w >= NPAIR) return;

    const int nn = lane & 15;
    const int koff = (lane >> 4) * 8;
    const int vA = w * 32 + nn;
    const int vB = vA + 16;
    const int vAc = min(vA, VOCAB - 1);
    const int vBc = min(vB, VOCAB - 1);

    const float* wrowA = Wout + (size_t)vAc * HDIM + koff;
    const float* wrowB = Wout + (size_t)vBc * HDIM + koff;
    const unsigned short* arow = h1bf + nn * HDIM + koff;

    f32x4 accA[4], accB[4];
    #pragma unroll
    for (int mt = 0; mt < 4; ++mt) { accA[mt] = (f32x4){0,0,0,0}; accB[mt] = (f32x4){0,0,0,0}; }

    float4 pa0 = *(const float4*)(wrowA);
    float4 pa1 = *(const float4*)(wrowA + 4);
    float4 pb0 = *(const float4*)(wrowB);
    float4 pb1 = *(const float4*)(wrowB + 4);

    #pragma unroll
    for (int ks = 0; ks < 16; ++ks) {
        float4 ca0 = pa0, ca1 = pa1, cb0 = pb0, cb1 = pb1;
        if (ks < 15) {
            pa0 = *(const float4*)(wrowA + 32 * (ks + 1));
            pa1 = *(const float4*)(wrowA + 32 * (ks + 1) + 4);
            pb0 = *(const float4*)(wrowB + 32 * (ks + 1));
            pb1 = *(const float4*)(wrowB + 32 * (ks + 1) + 4);
        }
        bf16x8 bA = pack8(ca0, ca1);
        bf16x8 bB = pack8(cb0, cb1);
        #pragma unroll
        for (int mt = 0; mt < 4; ++mt) {
            bf16x8 a = *(const bf16x8*)(arow + (size_t)mt * 16 * HDIM + 32 * ks);
            accA[mt] = __builtin_amdgcn_mfma_f32_16x16x32_bf16(a, bA, accA[mt], 0, 0, 0);
            accB[mt] = __builtin_amdgcn_mfma_f32_16x16x32_bf16(a, bB, accB[mt], 0, 0, 0);
        }
    }

    const int b0 = (lane >> 4) * 4;
    if (vA < VOCAB) {
        const float bias = bout[vA];
        #pragma unroll
        for (int mt = 0; mt < 4; ++mt)
            #pragma unroll
            for (int r = 0; r < 4; ++r)
                logits[(size_t)(mt * 16 + b0 + r) * VOCAB + vA] = accA[mt][r] + bias;
    }
    if (vB < VOCAB) {
        const float bias = bout[vB];
        #pragma unroll
        for (int mt = 0; mt < 4; ++mt)
            #pragma unroll
            for (int r = 0; r < 4; ++r)
                logits[(size_t)(mt * 16 + b0 + r) * VOCAB + vB] = accB[mt][r] + bias;
    }
}

// ---------------------------------------------------------------------------
extern "C" void kernel_launch(void* const* d_in, const int* in_sizes, int n_in,
                              void* d_out, int out_size, void* d_ws, size_t ws_size,
                              hipStream_t stream) {
    const int*   inputs = (const int*)d_in[0];
    const float* dec    = (const float*)d_in[1];
    const float* enc    = (const float*)d_in[2];
    const float* emb    = (const float*)d_in[3];
    const float* Wih0   = (const float*)d_in[4];
    const float* Whh0   = (const float*)d_in[5];
    const float* bih0   = (const float*)d_in[6];
    const float* bhh0   = (const float*)d_in[7];
    const float* Wih1   = (const float*)d_in[8];
    const float* Whh1   = (const float*)d_in[9];
    const float* bih1   = (const float*)d_in[10];
    const float* bhh1   = (const float*)d_in[11];
    const float* Wout   = (const float*)d_in[12];
    const float* bout   = (const float*)d_in[13];
    float* out = (float*)d_out;

    int P = 128;
    while (P > 4) {
        size_t need = ((size_t)P * BATCH * (HDIM + 2) + 2u * NCOL * 64) * sizeof(float)
                      + 2u * (BATCH * (EDIM + HDIM) + 4u * BH);
        if (need <= ws_size) break;
        P >>= 1;
    }
    const int rows = SEQ / P;

    float* w    = (float*)d_ws;
    float* pm   = w;
    float* pl   = pm + (size_t)P * BATCH;
    float* pacc = pl + (size_t)P * BATCH;
    float* part = pacc + (size_t)P * BATCH * HDIM;          // [2][3072][64]
    unsigned short* xbf  = (unsigned short*)(part + 2 * (size_t)NCOL * 64);
    unsigned short* d0bf = xbf + (size_t)BATCH * (EDIM + HDIM);
    unsigned short* d1bf = d0bf + BH;
    unsigned short* h0bf = d1bf + BH;
    unsigned short* h1bf = h0bf + BH;

    float* h0out = out + (size_t)BATCH * VOCAB;   // new_hidden[0]
    float* h1out = h0out + BH;                    // new_hidden[1]

    attn_partial<<<dim3(P / 4, BATCH), 256, 0, stream>>>(enc, dec, pm, pl, pacc, P, rows);
    attn_combine<<<BATCH, 512, 0, stream>>>(pm, pl, pacc, dec, emb, inputs, xbf, d0bf, d1bf, P);

    gru_gemm<EDIM + HDIM><<<dim3(48, 2), 256, 0, stream>>>(xbf, d0bf, Wih0, Whh0, part);
    gru_gate<<<128, 256, 0, stream>>>(part, dec, bih0, bhh0, h0out, h0bf);
    gru_gemm<HDIM><<<dim3(48, 2), 256, 0, stream>>>(h0bf, d1bf, Wih1, Whh1, part);
    gru_gate<<<128, 256, 0, stream>>>(part, dec + BH, bih1, bhh1, h1out, h1bf);

    const int NPAIR = (VOCAB + 31) / 32;
    vocab_proj_mfma<<<(NPAIR + 3) / 4, 256, 0, stream>>>(h1bf, Wout, bout, out);
}